// Round 4
// baseline (69.790 us; speedup 1.0000x reference)
//
#include <hip/hip_runtime.h>
#include <math.h>

// IntraVolume_Attention collapses algebraically:
//   scores[b,v,f,g] = c * x[b,v,f] * x[b,v,g],  c = dot(w_q,w_k)/sqrt(128)
//   out[b,v,d] = w_v[d] * mean_f( softmax_weighted_mean_g(x) with logits c*x_f*x_g )
// 67M exps, ~640 KB HBM -> transcendental/issue bound. Floor ~6 us
// (per SIMD: 1024 wave-exps*8cyc + 3072 wave-VALU*2cyc, shared issue port).
//
// R3 lesson: killing LDS reads changed nothing -> kernel was LATENCY bound at
// 1 block/CU (4 waves/SIMD). R4: split each row over 4 blocks -> 1024 blocks
// = 4 blocks/CU, 32 waves/CU (HW max), 128 exps/thread, 4 acc chains.
// Per-block scalar partial -> d_ws; tiny combine kernel applies w_v.

#if __has_builtin(__builtin_amdgcn_exp2f)
#define EXP2(x) __builtin_amdgcn_exp2f(x)   // raw v_exp_f32
#else
#define EXP2(x) exp2f(x)
#endif

#define F_DIM 512

__global__ __launch_bounds__(512) void intravol_p1(
    const float* __restrict__ x,    // [256, 512]
    const float* __restrict__ wq,   // [128]
    const float* __restrict__ wk,   // [128]
    float* __restrict__ part)       // [1024] partial sums (one per block)
{
    __shared__ __align__(16) float xs[F_DIM];
    __shared__ float pden[8][128];  // [g-slice][f-local]
    __shared__ float pnum[8][128];
    __shared__ float wmax[8], wmin[8], wsum[2];
    __shared__ float s_c, s_xmax, s_xmin;

    const int tid  = threadIdx.x;
    const int lane = tid & 63;
    const int wave = tid >> 6;
    const int row  = blockIdx.x >> 2;   // (b,v) row
    const int prt  = blockIdx.x & 3;    // which 128-f quarter

    // Stage full row; reduce max/min across all 8 waves.
    const float xv = x[row * F_DIM + tid];
    xs[tid] = xv;
    float mx = xv, mn = xv;
    for (int o = 32; o > 0; o >>= 1) {
        mx = fmaxf(mx, __shfl_down(mx, o));
        mn = fminf(mn, __shfl_down(mn, o));
    }
    if (lane == 0) { wmax[wave] = mx; wmin[wave] = mn; }
    __syncthreads();
    if (tid == 0) {
        float M = wmax[0], m_ = wmin[0];
        #pragma unroll
        for (int i = 1; i < 8; ++i) { M = fmaxf(M, wmax[i]); m_ = fminf(m_, wmin[i]); }
        s_xmax = M; s_xmin = m_;
    } else if (wave == 1) {             // concurrently: c = dot(wq,wk)/sqrt(128)
        float d = wq[lane] * wk[lane] + wq[lane + 64] * wk[lane + 64];
        for (int o = 32; o > 0; o >>= 1) d += __shfl_down(d, o);
        if (lane == 0) s_c = d * 0.08838834764831845f;
    }
    __syncthreads();

    // Thread = (f-pair, 64-g slice). Slice uniform per wave -> LDS broadcast.
    const float LOG2E = 1.4426950408889634f;
    const int sl = tid >> 6;            // == wave, g-slice
    const int fl = (tid & 63) << 1;     // local f (0..126, step 2)
    const int f  = (prt << 7) + fl;

    const float a0 = s_c * xs[f]     * LOG2E;
    const float a1 = s_c * xs[f + 1] * LOG2E;
    const float b0 = -((a0 >= 0.0f) ? a0 * s_xmax : a0 * s_xmin);
    const float b1 = -((a1 >= 0.0f) ? a1 * s_xmax : a1 * s_xmin);

    float d0 = 0.0f, d1 = 0.0f, n0 = 0.0f, n1 = 0.0f;
    const float4* xs4 = (const float4*)&xs[sl << 6];
    #pragma unroll
    for (int i = 0; i < 16; ++i) {      // 16 broadcast ds_read_b128
        const float4 v = xs4[i];
        const float xg_[4] = { v.x, v.y, v.z, v.w };
        #pragma unroll
        for (int j = 0; j < 4; ++j) {
            const float xg = xg_[j];
            const float e0 = EXP2(fmaf(a0, xg, b0));
            const float e1 = EXP2(fmaf(a1, xg, b1));
            d0 += e0; n0 = fmaf(e0, xg, n0);
            d1 += e1; n1 = fmaf(e1, xg, n1);
        }
    }
    pden[sl][fl] = d0; pden[sl][fl + 1] = d1;   // 8B stride: 2-way bank, free
    pnum[sl][fl] = n0; pnum[sl][fl + 1] = n1;
    __syncthreads();

    // Combine 8 slices per f, s_f = num/den, sum over the 128 local f's.
    float sf = 0.0f;
    if (tid < 128) {
        float D = 0.0f, N = 0.0f;
        #pragma unroll
        for (int s = 0; s < 8; ++s) { D += pden[s][tid]; N += pnum[s][tid]; }
        sf = N / D;
    }
    float t = sf;
    for (int o = 32; o > 0; o >>= 1) t += __shfl_down(t, o);
    if (lane == 0 && wave < 2) wsum[wave] = t;
    __syncthreads();
    if (tid == 0) part[blockIdx.x] = wsum[0] + wsum[1];
}

__global__ __launch_bounds__(128) void intravol_p2(
    const float* __restrict__ part,  // [1024]
    const float* __restrict__ wv,    // [128]
    float* __restrict__ out)         // [256, 128]
{
    const int r = blockIdx.x;
    const int t = threadIdx.x;
    const float S = part[4 * r] + part[4 * r + 1] + part[4 * r + 2] + part[4 * r + 3];
    out[r * 128 + t] = S * (1.0f / (float)F_DIM) * wv[t];
}

extern "C" void kernel_launch(void* const* d_in, const int* in_sizes, int n_in,
                              void* d_out, int out_size, void* d_ws, size_t ws_size,
                              hipStream_t stream) {
    const float* x  = (const float*)d_in[0];  // [8,32,512]
    const float* wq = (const float*)d_in[1];  // [1,128]
    const float* wk = (const float*)d_in[2];  // [1,128]
    const float* wv = (const float*)d_in[3];  // [1,128]
    float* out  = (float*)d_out;              // [8,32,128]
    float* part = (float*)d_ws;               // 1024 floats of scratch

    intravol_p1<<<1024, 512, 0, stream>>>(x, wq, wk, part);
    intravol_p2<<<256, 128, 0, stream>>>(part, wv, out);
}